// Round 4
// baseline (269.569 us; speedup 1.0000x reference)
//
#include <hip/hip_runtime.h>
#include <hip/hip_cooperative_groups.h>

namespace cg = cooperative_groups;

// EdgeConv on dense bipartite graph: A=256, U=1024, D=64.
// out[a,u] = edge@W3t - (relu(edge@W1b+c1[a]) + relu(edge@W2b+c2[u]))@W3b + s3[a] + s4[u]
// with c1 = ap_hid@W1t+b1, c2 = ue_hid@W2t+b2, s3 = ap_sum@W3b, s4 = ue_sum@W3b+b3.
//
// R4: cooperative kernel with SMALL LDS (9 KiB) so 512-block validation passes:
// phaseA (sums via atomics) -> grid.sync -> phaseB (s3/s4 inline via MFMA,
// recompute t per slice with wave-private LDS round-trip, fused epilogue).
// Return code of the cooperative launch is checked; fallback = 2 plain kernels.

typedef short short8 __attribute__((ext_vector_type(8)));
typedef float f32x4 __attribute__((ext_vector_type(4)));

__device__ __forceinline__ unsigned short f2bf(float f) {
  unsigned int u = __float_as_uint(f);
  return (unsigned short)((u + 0x7FFFu + ((u >> 16) & 1u)) >> 16);  // RNE
}

__device__ __forceinline__ f32x4 mfma16(short8 a, short8 b, f32x4 c) {
  return __builtin_amdgcn_mfma_f32_16x16x32_bf16(a, b, c, 0, 0, 0);
}

__device__ __forceinline__ short8 cvt8(float4 a, float4 b) {
  short8 r;
  r[0] = (short)f2bf(a.x); r[1] = (short)f2bf(a.y);
  r[2] = (short)f2bf(a.z); r[3] = (short)f2bf(a.w);
  r[4] = (short)f2bf(b.x); r[5] = (short)f2bf(b.y);
  r[6] = (short)f2bf(b.z); r[7] = (short)f2bf(b.w);
  return r;
}

__device__ __forceinline__ void cvt16(const float4& e0, const float4& e1,
                                      const float4& e2, const float4& e3,
                                      short8& a0, short8& a1) {
  a0 = cvt8(e0, e1);
  a1 = cvt8(e2, e3);
}

__device__ __forceinline__ void rowmlp_row(const float* __restrict__ in,
                                           const float* __restrict__ W,
                                           const float* __restrict__ bias,
                                           float* __restrict__ out, int r, int lane) {
  float rv = in[r * 64 + lane];
  float acc = bias ? bias[lane] : 0.f;
#pragma unroll
  for (int k = 0; k < 64; k++) acc += __shfl(rv, k, 64) * W[k * 64 + lane];
  out[r * 64 + lane] = acc;
}

// Fused setup: zero accumulators, build Wt (bf16, n-major, 4 sections), c1, c2.
// Wt rows 0-63: W1_bot^T, 64-127: W2_bot^T, 128-191: W3_top^T, 192-255: W3_bot^T
__global__ __launch_bounds__(256) void k_prep(
    const float* __restrict__ ap_hid, const float* __restrict__ ue_hid,
    const float* __restrict__ W1, const float* __restrict__ b1,
    const float* __restrict__ W2, const float* __restrict__ b2,
    const float* __restrict__ W3, unsigned short* __restrict__ Wt,
    float* __restrict__ acc_zero, float* __restrict__ c1, float* __restrict__ c2) {
  int bx = blockIdx.x, tid = threadIdx.x;
  if (bx < 320) {
    int i = bx * 256 + tid;
    if (i < 81920) acc_zero[i] = 0.f;
  } else if (bx < 384) {
    int idx = (bx - 320) * 256 + tid;  // 16384 total
    int r = idx >> 6, k = idx & 63;
    int sec = r >> 6, d = r & 63;
    float v;
    if (sec == 0)      v = W1[(64 + k) * 64 + d];
    else if (sec == 1) v = W2[(64 + k) * 64 + d];
    else if (sec == 2) v = W3[k * 64 + d];
    else               v = W3[(64 + k) * 64 + d];
    Wt[r * 64 + k] = f2bf(v);
  } else if (bx < 448) {
    int r = (bx - 384) * 4 + (tid >> 6);
    rowmlp_row(ap_hid, W1, b1, c1, r, tid & 63);
  } else {  // bx in [448, 704)
    int r = (bx - 448) * 4 + (tid >> 6);
    rowmlp_row(ue_hid, W2, b2, c2, r, tid & 63);
  }
}

// Phase A: ap_sum[a] = sum_u relu(edge@W1b + c1[a]); ue_sum[u] = sum_a relu(edge@W2b + c2[u]).
// 512 blocks x 256: 8 a-slices x one 64-u panel; edge A-frags direct from global
// with distance-1 register prefetch. No LDS, no barriers.
__device__ __forceinline__ void phaseA(
    const float* __restrict__ edge, const unsigned short* __restrict__ Wt,
    const float* __restrict__ c1, const float* __restrict__ c2,
    float* __restrict__ ap_sum, float* __restrict__ ue_sum) {
  int tid = threadIdx.x, lane = tid & 63, w = tid >> 6;
  int fr = lane & 15, fq = lane >> 4;
  int bx = blockIdx.x;
  int a0 = (bx >> 4) * 8, u0 = (bx & 15) * 64;
  const float* erow = edge + (u0 + w * 16 + fr) * 64 + fq * 8;

  short8 bw[8][2];  // tiles 0-3: W1b, 4-7: W2b
#pragma unroll
  for (int nt = 0; nt < 8; nt++) {
    bw[nt][0] = *(const short8*)(Wt + (nt * 16 + fr) * 64 + fq * 8);
    bw[nt][1] = *(const short8*)(Wt + (nt * 16 + fr) * 64 + 32 + fq * 8);
  }
  float c2v[4][4];
#pragma unroll
  for (int j = 0; j < 4; j++)
#pragma unroll
    for (int i = 0; i < 4; i++)
      c2v[j][i] = c2[(u0 + w * 16 + fq * 4 + i) * 64 + j * 16 + fr];
  float ureg[4][4] = {};

  const float* p0 = erow + a0 * 65536;
  float4 e0 = *(const float4*)(p0);
  float4 e1 = *(const float4*)(p0 + 4);
  float4 e2 = *(const float4*)(p0 + 32);
  float4 e3 = *(const float4*)(p0 + 36);
  float c1v[4];
#pragma unroll
  for (int j = 0; j < 4; j++) c1v[j] = c1[a0 * 64 + j * 16 + fr];

  for (int c = 0; c < 8; c++) {
    int a = a0 + c;
    float4 n0, n1, n2, n3;
    float nc1[4];
    if (c < 7) {
      const float* np = erow + (a + 1) * 65536;
      n0 = *(const float4*)(np);
      n1 = *(const float4*)(np + 4);
      n2 = *(const float4*)(np + 32);
      n3 = *(const float4*)(np + 36);
#pragma unroll
      for (int j = 0; j < 4; j++) nc1[j] = c1[(a + 1) * 64 + j * 16 + fr];
    }
    short8 af0, af1;
    cvt16(e0, e1, e2, e3, af0, af1);
#pragma unroll
    for (int j = 0; j < 4; j++) {
      f32x4 A1 = {0.f, 0.f, 0.f, 0.f};
      A1 = mfma16(af0, bw[j][0], A1);
      A1 = mfma16(af1, bw[j][1], A1);
      f32x4 A2 = {0.f, 0.f, 0.f, 0.f};
      A2 = mfma16(af0, bw[4 + j][0], A2);
      A2 = mfma16(af1, bw[4 + j][1], A2);
      float cv = c1v[j];
      float rs = fmaxf(A1[0] + cv, 0.f) + fmaxf(A1[1] + cv, 0.f) +
                 fmaxf(A1[2] + cv, 0.f) + fmaxf(A1[3] + cv, 0.f);
#pragma unroll
      for (int i = 0; i < 4; i++) ureg[j][i] += fmaxf(A2[i] + c2v[j][i], 0.f);
      rs += __shfl_xor(rs, 16, 64);
      rs += __shfl_xor(rs, 32, 64);
      if (lane < 16) atomicAdd(&ap_sum[a * 64 + j * 16 + lane], rs);
    }
    if (c < 7) {
      e0 = n0; e1 = n1; e2 = n2; e3 = n3;
#pragma unroll
      for (int j = 0; j < 4; j++) c1v[j] = nc1[j];
    }
  }
#pragma unroll
  for (int j = 0; j < 4; j++)
#pragma unroll
    for (int i = 0; i < 4; i++)
      atomicAdd(&ue_sum[(u0 + w * 16 + fq * 4 + i) * 64 + j * 16 + fr], ureg[j][i]);
}

// Phase B: out = P3 - t@W3b + s3[a] + s4[u] + b3; t recomputed per slice.
// s3/s4 computed inline via MFMA from ap_sum/ue_sum. All weight frags in regs.
__device__ __forceinline__ void phaseB(
    const float* __restrict__ edge, const unsigned short* __restrict__ Wt,
    const float* __restrict__ c1, const float* __restrict__ c2,
    const float* __restrict__ ap_sum, const float* __restrict__ ue_sum,
    const float* __restrict__ b3, float* __restrict__ out,
    unsigned short* t_lds) {
  int tid = threadIdx.x, lane = tid & 63, w = tid >> 6;
  int fr = lane & 15, fq = lane >> 4;
  int bx = blockIdx.x;
  int a0 = (bx >> 4) * 8, u0 = (bx & 15) * 64;
  const float* erow = edge + (u0 + w * 16 + fr) * 64 + fq * 8;

  // prefetch slice 0 edge (L2/L3-hot from phase A)
  const float* p0 = erow + a0 * 65536;
  float4 e0 = *(const float4*)(p0);
  float4 e1 = *(const float4*)(p0 + 4);
  float4 e2 = *(const float4*)(p0 + 32);
  float4 e3 = *(const float4*)(p0 + 36);

  short8 bwA[4][2], bwB[4][2], bwT[4][2], bwG[4][2];
#pragma unroll
  for (int j = 0; j < 4; j++) {
#pragma unroll
    for (int ks = 0; ks < 2; ks++) {
      bwA[j][ks] = *(const short8*)(Wt + (j * 16 + fr) * 64 + ks * 32 + fq * 8);
      bwB[j][ks] = *(const short8*)(Wt + (64 + j * 16 + fr) * 64 + ks * 32 + fq * 8);
      bwT[j][ks] = *(const short8*)(Wt + (128 + j * 16 + fr) * 64 + ks * 32 + fq * 8);
      bwG[j][ks] = *(const short8*)(Wt + (192 + j * 16 + fr) * 64 + ks * 32 + fq * 8);
    }
  }
  float c1v[4], b3v[4];
#pragma unroll
  for (int j = 0; j < 4; j++) {
    c1v[j] = c1[a0 * 64 + j * 16 + fr];
    b3v[j] = b3[j * 16 + fr];
  }
  float c2v[4][4];
#pragma unroll
  for (int j = 0; j < 4; j++)
#pragma unroll
    for (int i = 0; i < 4; i++)
      c2v[j][i] = c2[(u0 + w * 16 + fq * 4 + i) * 64 + j * 16 + fr];

  // s4 for this wave's 16 u rows (C-layout matches epilogue exactly)
  const float* up = ue_sum + (u0 + w * 16 + fr) * 64 + fq * 8;
  short8 sf0 = cvt8(*(const float4*)(up), *(const float4*)(up + 4));
  short8 sf1 = cvt8(*(const float4*)(up + 32), *(const float4*)(up + 36));
  f32x4 s4C[4];
#pragma unroll
  for (int j = 0; j < 4; j++) {
    f32x4 t = {0.f, 0.f, 0.f, 0.f};
    t = mfma16(sf0, bwG[j][0], t);
    t = mfma16(sf1, bwG[j][1], t);
    s4C[j] = t;
  }
  // s3 for the block's 8 a rows (A rows replicated mod 8; broadcast via shfl)
  const float* apk = ap_sum + (a0 + (fr & 7)) * 64 + fq * 8;
  short8 pa0 = cvt8(*(const float4*)(apk), *(const float4*)(apk + 4));
  short8 pa1 = cvt8(*(const float4*)(apk + 32), *(const float4*)(apk + 36));
  f32x4 s3C[4];
#pragma unroll
  for (int j = 0; j < 4; j++) {
    f32x4 t = {0.f, 0.f, 0.f, 0.f};
    t = mfma16(pa0, bwG[j][0], t);
    t = mfma16(pa1, bwG[j][1], t);
    s3C[j] = t;
  }

  for (int c = 0; c < 8; c++) {
    float4 n0, n1, n2, n3;
    float nc1[4];
    if (c < 7) {
      const float* np = erow + (a0 + c + 1) * 65536;
      n0 = *(const float4*)(np);
      n1 = *(const float4*)(np + 4);
      n2 = *(const float4*)(np + 32);
      n3 = *(const float4*)(np + 36);
#pragma unroll
      for (int j = 0; j < 4; j++) nc1[j] = c1[(a0 + c + 1) * 64 + j * 16 + fr];
    }
    short8 af0, af1;
    cvt16(e0, e1, e2, e3, af0, af1);

    f32x4 accP3[4];
#pragma unroll
    for (int j = 0; j < 4; j++) {
      f32x4 a1 = {0.f, 0.f, 0.f, 0.f};
      a1 = mfma16(af0, bwA[j][0], a1);
      a1 = mfma16(af1, bwA[j][1], a1);
      f32x4 a2 = {0.f, 0.f, 0.f, 0.f};
      a2 = mfma16(af0, bwB[j][0], a2);
      a2 = mfma16(af1, bwB[j][1], a2);
      f32x4 p3 = {0.f, 0.f, 0.f, 0.f};
      p3 = mfma16(af0, bwT[j][0], p3);
      p3 = mfma16(af1, bwT[j][1], p3);
      accP3[j] = p3;
#pragma unroll
      for (int i = 0; i < 4; i++) {
        float tv = fmaxf(a1[i] + c1v[j], 0.f) + fmaxf(a2[i] + c2v[j][i], 0.f);
        t_lds[(w * 16 + fq * 4 + i) * 72 + j * 16 + fr] = f2bf(tv);  // wave-private
      }
    }
    // t round-trip (wave-private rows; DS in-order per wave, no barrier)
    short8 tf0 = *(const short8*)&t_lds[(w * 16 + fr) * 72 + fq * 8];
    short8 tf1 = *(const short8*)&t_lds[(w * 16 + fr) * 72 + 32 + fq * 8];
    float* outb = out + ((a0 + c) * 1024 + u0 + w * 16) * 64;
#pragma unroll
    for (int j = 0; j < 4; j++) {
      f32x4 g = {0.f, 0.f, 0.f, 0.f};
      g = mfma16(tf0, bwG[j][0], g);
      g = mfma16(tf1, bwG[j][1], g);
      float s3v = __shfl(s3C[j][c & 3], ((c >> 2) << 4) | (lane & 15), 64);
#pragma unroll
      for (int i = 0; i < 4; i++)
        outb[(fq * 4 + i) * 64 + j * 16 + fr] =
            accP3[j][i] - g[i] + s3v + s4C[j][i] + b3v[j];
    }
    if (c < 7) {
      e0 = n0; e1 = n1; e2 = n2; e3 = n3;
#pragma unroll
      for (int j = 0; j < 4; j++) c1v[j] = nc1[j];
    }
  }
}

__global__ __launch_bounds__(256, 2) void k_main(
    const float* __restrict__ edge, const unsigned short* __restrict__ Wt,
    const float* __restrict__ c1, const float* __restrict__ c2,
    float* __restrict__ ap_sum, float* __restrict__ ue_sum,
    const float* __restrict__ b3, float* __restrict__ out) {
  __shared__ unsigned short t_lds[64 * 72];  // 9216 B only
  phaseA(edge, Wt, c1, c2, ap_sum, ue_sum);
  __threadfence();
  cg::this_grid().sync();
  phaseB(edge, Wt, c1, c2, ap_sum, ue_sum, b3, out, t_lds);
}

// Plain fallbacks (identical bodies) if cooperative launch is rejected.
__global__ __launch_bounds__(256, 2) void k_phA(
    const float* __restrict__ edge, const unsigned short* __restrict__ Wt,
    const float* __restrict__ c1, const float* __restrict__ c2,
    float* __restrict__ ap_sum, float* __restrict__ ue_sum) {
  phaseA(edge, Wt, c1, c2, ap_sum, ue_sum);
}

__global__ __launch_bounds__(256, 2) void k_phB(
    const float* __restrict__ edge, const unsigned short* __restrict__ Wt,
    const float* __restrict__ c1, const float* __restrict__ c2,
    const float* __restrict__ ap_sum, const float* __restrict__ ue_sum,
    const float* __restrict__ b3, float* __restrict__ out) {
  __shared__ unsigned short t_lds[64 * 72];
  phaseB(edge, Wt, c1, c2, ap_sum, ue_sum, b3, out, t_lds);
}

extern "C" void kernel_launch(void* const* d_in, const int* in_sizes, int n_in,
                              void* d_out, int out_size, void* d_ws, size_t ws_size,
                              hipStream_t stream) {
  const float* ap_hid = (const float*)d_in[0];
  const float* ue_hid = (const float*)d_in[1];
  const float* edge   = (const float*)d_in[2];
  const float* W1     = (const float*)d_in[3];
  const float* b1     = (const float*)d_in[4];
  const float* W2     = (const float*)d_in[5];
  const float* b2     = (const float*)d_in[6];
  const float* W3     = (const float*)d_in[7];
  const float* b3     = (const float*)d_in[8];
  float* outp = (float*)d_out;

  char* ws = (char*)d_ws;
  unsigned short* Wt = (unsigned short*)ws;          //  32768 B
  float* c1     = (float*)(ws + 32768);              //  65536 B
  float* c2     = (float*)(ws + 98304);              // 262144 B
  float* ap_sum = (float*)(ws + 360448);             //  65536 B
  float* ue_sum = (float*)(ws + 425984);             // 262144 B (contiguous after ap_sum)

  k_prep<<<704, 256, 0, stream>>>(ap_hid, ue_hid, W1, b1, W2, b2, W3, Wt,
                                  (float*)(ws + 360448), c1, c2);

  void* args[] = {(void*)&edge, (void*)&Wt, (void*)&c1, (void*)&c2,
                  (void*)&ap_sum, (void*)&ue_sum, (void*)&b3, (void*)&outp};
  hipError_t err = hipLaunchCooperativeKernel((const void*)k_main, dim3(512),
                                              dim3(256), args, 0, stream);
  if (err != hipSuccess) {
    (void)hipGetLastError();  // clear error state; use plain 2-kernel path
    k_phA<<<512, 256, 0, stream>>>(edge, Wt, c1, c2, ap_sum, ue_sum);
    k_phB<<<512, 256, 0, stream>>>(edge, Wt, c1, c2, ap_sum, ue_sum, b3, outp);
  }
}

// Round 5
// 244.936 us; speedup vs baseline: 1.1006x; 1.1006x over previous
//
#include <hip/hip_runtime.h>

// EdgeConv on dense bipartite graph: A=256, U=1024, D=64.
// out[a,u] = edge@W3t - (relu(edge@W1b+c1[a]) + relu(edge@W2b+c2[u]))@W3b + s3[a] + s4[u]
// with c1 = ap_hid@W1t+b1, c2 = ue_hid@W2t+b2, s3 = ap_sum@W3b, s4 = ue_sum@W3b+b3.
//
// R5: single compute pass over edge. k_pass1 stages edge via global_load_lds
// (DMA cannot be register-demoted like R2-R4's "prefetch" loads were - VGPR=36
// proved the compiler serialized them), double-buffered, XOR-swizzled chunks.
// It writes partial = P3 - t@W3b as packed bf16 (33.5 MB in ws) + atomic sums.
// k_mid: s3/s4+b3. k_pass2: pure streaming add with nontemporal out stores.

typedef short short8 __attribute__((ext_vector_type(8)));
typedef float f32x4 __attribute__((ext_vector_type(4)));
typedef unsigned int u32;

__device__ __forceinline__ unsigned short f2bf(float f) {
  u32 u = __float_as_uint(f);
  return (unsigned short)((u + 0x7FFFu + ((u >> 16) & 1u)) >> 16);  // RNE
}

__device__ __forceinline__ f32x4 mfma16(short8 a, short8 b, f32x4 c) {
  return __builtin_amdgcn_mfma_f32_16x16x32_bf16(a, b, c, 0, 0, 0);
}

__device__ __forceinline__ short8 cvt8(float4 a, float4 b) {
  short8 r;
  r[0] = (short)f2bf(a.x); r[1] = (short)f2bf(a.y);
  r[2] = (short)f2bf(a.z); r[3] = (short)f2bf(a.w);
  r[4] = (short)f2bf(b.x); r[5] = (short)f2bf(b.y);
  r[6] = (short)f2bf(b.z); r[7] = (short)f2bf(b.w);
  return r;
}

// async global->LDS DMA, 16 B per lane, lands at ldsbase + lane*16
__device__ __forceinline__ void gl_lds16(const float* g, float* l) {
  __builtin_amdgcn_global_load_lds(
      (const __attribute__((address_space(1))) u32*)g,
      (__attribute__((address_space(3))) u32*)l, 16, 0, 0);
}

// Stage one 16-row x 256B slice panel for wave w. LDS slot cc (16B chunks)
// of row rl holds global chunk cc ^ (rl&7)  (involution: reader XORs again).
__device__ __forceinline__ void stage_slice(const float* __restrict__ edge,
                                            int a, int u0, int w, int lane,
                                            float* __restrict__ buf) {
#pragma unroll
  for (int q = 0; q < 4; q++) {
    int rl = q * 4 + (lane >> 4);
    int cg = (lane & 15) ^ (rl & 7);
    const float* g = edge + (a * 1024 + u0 + w * 16 + rl) * 64 + cg * 4;
    gl_lds16(g, buf + w * 1024 + q * 256);
  }
}

__device__ __forceinline__ void rowmlp_row(const float* __restrict__ in,
                                           const float* __restrict__ W,
                                           const float* __restrict__ bias,
                                           float* __restrict__ out, int r, int lane) {
  float rv = in[r * 64 + lane];
  float acc = bias ? bias[lane] : 0.f;
#pragma unroll
  for (int k = 0; k < 64; k++) acc += __shfl(rv, k, 64) * W[k * 64 + lane];
  out[r * 64 + lane] = acc;
}

// Fused setup: zero accumulators, build Wt (bf16, n-major, 4 sections), c1, c2.
// Wt rows 0-63: W1_bot^T, 64-127: W2_bot^T, 128-191: W3_top^T, 192-255: W3_bot^T
__global__ __launch_bounds__(256) void k_prep(
    const float* __restrict__ ap_hid, const float* __restrict__ ue_hid,
    const float* __restrict__ W1, const float* __restrict__ b1,
    const float* __restrict__ W2, const float* __restrict__ b2,
    const float* __restrict__ W3, unsigned short* __restrict__ Wt,
    float* __restrict__ acc_zero, float* __restrict__ c1, float* __restrict__ c2) {
  int bx = blockIdx.x, tid = threadIdx.x;
  if (bx < 320) {
    int i = bx * 256 + tid;
    if (i < 81920) acc_zero[i] = 0.f;
  } else if (bx < 384) {
    int idx = (bx - 320) * 256 + tid;  // 16384 total
    int r = idx >> 6, k = idx & 63;
    int sec = r >> 6, d = r & 63;
    float v;
    if (sec == 0)      v = W1[(64 + k) * 64 + d];
    else if (sec == 1) v = W2[(64 + k) * 64 + d];
    else if (sec == 2) v = W3[k * 64 + d];
    else               v = W3[(64 + k) * 64 + d];
    Wt[r * 64 + k] = f2bf(v);
  } else if (bx < 448) {
    int r = (bx - 384) * 4 + (tid >> 6);
    rowmlp_row(ap_hid, W1, b1, c1, r, tid & 63);
  } else {  // bx in [448, 704)
    int r = (bx - 448) * 4 + (tid >> 6);
    rowmlp_row(ue_hid, W2, b2, c2, r, tid & 63);
  }
}

// s3 = ap_sum@W3b; s4b = ue_sum@W3b + b3
__global__ __launch_bounds__(256) void k_mid(
    const float* __restrict__ ap_sum, const float* __restrict__ ue_sum,
    const float* __restrict__ W3, const float* __restrict__ b3,
    float* __restrict__ s3, float* __restrict__ s4b) {
  int bx = blockIdx.x, tid = threadIdx.x;
  if (bx < 64) {
    int r = bx * 4 + (tid >> 6);
    rowmlp_row(ap_sum, W3 + 4096, nullptr, s3, r, tid & 63);
  } else {  // [64, 320)
    int r = (bx - 64) * 4 + (tid >> 6);
    rowmlp_row(ue_sum, W3 + 4096, b3, s4b, r, tid & 63);
  }
}

// Pass 1: ONE pass over edge. 1024 blocks = 64 a-groups(4 slices) x 16 u-panels.
// Per slice: P1,P2 -> t (LDS round-trip, wave-private) + relu sums (atomics);
// P3; partial = P3 - t@W3b packed to bf16 (2 dwords per (i,jj) per lane,
// 32 B contiguous per lane). Edge staged by global_load_lds double-buffer.
__global__ __launch_bounds__(256, 3) void k_pass1(
    const float* __restrict__ edge, const unsigned short* __restrict__ Wt,
    const float* __restrict__ c1, const float* __restrict__ c2,
    float* __restrict__ ap_sum, float* __restrict__ ue_sum,
    u32* __restrict__ partial) {
  __shared__ float Ebuf[2][4096];          // 2 x 16 KB edge slice buffers
  __shared__ unsigned short t_lds[64 * 72];  // 9216 B
  int tid = threadIdx.x, lane = tid & 63, w = tid >> 6;
  int fr = lane & 15, fq = lane >> 4;
  int bx = blockIdx.x;
  int a0 = (bx >> 4) * 4, pnl = bx & 15, u0 = pnl * 64;

  // kick off DMA for slice 0 first; weight/c2 loads overlap its latency
  stage_slice(edge, a0, u0, w, lane, &Ebuf[0][0]);

  short8 bwA[4][2], bwB[4][2], bwT[4][2], bwG[4][2];
#pragma unroll
  for (int j = 0; j < 4; j++) {
#pragma unroll
    for (int ks = 0; ks < 2; ks++) {
      bwA[j][ks] = *(const short8*)(Wt + (j * 16 + fr) * 64 + ks * 32 + fq * 8);
      bwB[j][ks] = *(const short8*)(Wt + (64 + j * 16 + fr) * 64 + ks * 32 + fq * 8);
      bwT[j][ks] = *(const short8*)(Wt + (128 + j * 16 + fr) * 64 + ks * 32 + fq * 8);
      bwG[j][ks] = *(const short8*)(Wt + (192 + j * 16 + fr) * 64 + ks * 32 + fq * 8);
    }
  }
  float c2v[4][4];
#pragma unroll
  for (int j = 0; j < 4; j++)
#pragma unroll
    for (int i = 0; i < 4; i++)
      c2v[j][i] = c2[(u0 + w * 16 + fq * 4 + i) * 64 + j * 16 + fr];
  float ureg[4][4] = {};

  int sw = fr & 7;
  for (int c = 0; c < 4; c++) {
    int a = a0 + c;
    // read slice c from LDS (compiler inserts the vmcnt wait; stage(c) has
    // been in flight for a full previous iteration)
    const float* rb = &Ebuf[c & 1][w * 1024 + fr * 64];
    float4 f0 = *(const float4*)(rb + ((fq * 2) ^ sw) * 4);
    float4 f1 = *(const float4*)(rb + ((fq * 2 + 1) ^ sw) * 4);
    float4 f2 = *(const float4*)(rb + (8 + ((fq * 2) ^ sw)) * 4);
    float4 f3 = *(const float4*)(rb + (8 + ((fq * 2 + 1) ^ sw)) * 4);
    asm volatile("" ::: "memory");  // keep the next stage AFTER these ds_reads
    if (c < 3) stage_slice(edge, a + 1, u0, w, lane, &Ebuf[(c + 1) & 1][0]);
    asm volatile("" ::: "memory");

    float c1v[4];
#pragma unroll
    for (int j = 0; j < 4; j++) c1v[j] = c1[a * 64 + j * 16 + fr];
    short8 af0 = cvt8(f0, f1);
    short8 af1 = cvt8(f2, f3);

    f32x4 accP3[4];
#pragma unroll
    for (int j = 0; j < 4; j++) {
      f32x4 A1 = {0.f, 0.f, 0.f, 0.f};
      A1 = mfma16(af0, bwA[j][0], A1);
      A1 = mfma16(af1, bwA[j][1], A1);
      f32x4 A2 = {0.f, 0.f, 0.f, 0.f};
      A2 = mfma16(af0, bwB[j][0], A2);
      A2 = mfma16(af1, bwB[j][1], A2);
      f32x4 P3 = {0.f, 0.f, 0.f, 0.f};
      P3 = mfma16(af0, bwT[j][0], P3);
      P3 = mfma16(af1, bwT[j][1], P3);
      accP3[j] = P3;
      float rs = 0.f;
#pragma unroll
      for (int i = 0; i < 4; i++) {
        float r1 = fmaxf(A1[i] + c1v[j], 0.f);
        float r2 = fmaxf(A2[i] + c2v[j][i], 0.f);
        rs += r1;
        ureg[j][i] += r2;
        t_lds[(w * 16 + fq * 4 + i) * 72 + j * 16 + fr] = f2bf(r1 + r2);
      }
      rs += __shfl_xor(rs, 16, 64);
      rs += __shfl_xor(rs, 32, 64);
      if (lane < 16) atomicAdd(&ap_sum[a * 64 + j * 16 + lane], rs);
    }
    // t round-trip (wave-private rows; DS in-order per wave, no barrier)
    short8 tf0 = *(const short8*)&t_lds[(w * 16 + fr) * 72 + fq * 8];
    short8 tf1 = *(const short8*)&t_lds[(w * 16 + fr) * 72 + 32 + fq * 8];
#pragma unroll
    for (int j = 0; j < 4; j++) {
      f32x4 g = {0.f, 0.f, 0.f, 0.f};
      g = mfma16(tf0, bwG[j][0], g);
      g = mfma16(tf1, bwG[j][1], g);
#pragma unroll
      for (int i = 0; i < 4; i++) accP3[j][i] -= g[i];  // partial (no s3/s4 yet)
    }
    // pack 16 bf16 -> 8 dwords -> 32 B contiguous per lane
    u32 r8[8];
#pragma unroll
    for (int i = 0; i < 4; i++)
#pragma unroll
      for (int jj = 0; jj < 2; jj++)
        r8[i * 2 + jj] = (u32)f2bf(accP3[2 * jj][i]) |
                         ((u32)f2bf(accP3[2 * jj + 1][i]) << 16);
    u32* pp = partial + (((a * 16 + pnl) * 4 + w) * 64 + lane) * 8;
    *(uint4*)pp = make_uint4(r8[0], r8[1], r8[2], r8[3]);
    *(uint4*)(pp + 4) = make_uint4(r8[4], r8[5], r8[6], r8[7]);
  }
#pragma unroll
  for (int j = 0; j < 4; j++)
#pragma unroll
    for (int i = 0; i < 4; i++)
      atomicAdd(&ue_sum[(u0 + w * 16 + fq * 4 + i) * 64 + j * 16 + fr], ureg[j][i]);
}

// Pass 2: out = unpack(partial) + s3[a] + s4b[u]. Pure streaming.
// Wave lanes mirror pass1 geometry exactly, so stores coalesce identically.
__global__ __launch_bounds__(256) void k_pass2(
    const u32* __restrict__ partial, const float* __restrict__ s3,
    const float* __restrict__ s4b, float* __restrict__ out) {
  int t0 = blockIdx.x * 256 + threadIdx.x;
  uint4 pa[4], pb[4];
#pragma unroll
  for (int it = 0; it < 4; it++) {
    const uint4* pp = (const uint4*)(partial + (t0 + it * 262144) * 8);
    pa[it] = pp[0];
    pb[it] = pp[1];
  }
#pragma unroll
  for (int it = 0; it < 4; it++) {
    int rec = t0 + it * 262144;
    int l = rec & 63, w = (rec >> 6) & 3, p = (rec >> 8) & 15, a = rec >> 12;
    int fr = l & 15, fq = l >> 4;
    int ub = p * 64 + w * 16 + fq * 4;
    float s3v[4];
#pragma unroll
    for (int j = 0; j < 4; j++) s3v[j] = s3[a * 64 + j * 16 + fr];
    u32 d[8] = {pa[it].x, pa[it].y, pa[it].z, pa[it].w,
                pb[it].x, pb[it].y, pb[it].z, pb[it].w};
#pragma unroll
    for (int i = 0; i < 4; i++) {
      const float* s4r = s4b + (ub + i) * 64 + fr;
      float* outr = out + (a * 1024 + ub + i) * 64 + fr;
#pragma unroll
      for (int j = 0; j < 4; j++) {
        u32 dw = d[i * 2 + (j >> 1)];
        u32 bits = (j & 1) ? (dw & 0xFFFF0000u) : (dw << 16);
        float v = __uint_as_float(bits) + s3v[j] + s4r[j * 16];
        __builtin_nontemporal_store(v, outr + j * 16);
      }
    }
  }
}

extern "C" void kernel_launch(void* const* d_in, const int* in_sizes, int n_in,
                              void* d_out, int out_size, void* d_ws, size_t ws_size,
                              hipStream_t stream) {
  const float* ap_hid = (const float*)d_in[0];
  const float* ue_hid = (const float*)d_in[1];
  const float* edge   = (const float*)d_in[2];
  const float* W1     = (const float*)d_in[3];
  const float* b1     = (const float*)d_in[4];
  const float* W2     = (const float*)d_in[5];
  const float* b2     = (const float*)d_in[6];
  const float* W3     = (const float*)d_in[7];
  const float* b3     = (const float*)d_in[8];
  float* outp = (float*)d_out;

  char* ws = (char*)d_ws;
  unsigned short* Wt = (unsigned short*)ws;          //  32768 B
  float* c1     = (float*)(ws + 32768);              //  65536 B
  float* c2     = (float*)(ws + 98304);              // 262144 B
  float* ap_sum = (float*)(ws + 360448);             //  65536 B
  float* ue_sum = (float*)(ws + 425984);             // 262144 B (contiguous after ap_sum)
  float* s3     = (float*)(ws + 688128);             //  65536 B
  float* s4b    = (float*)(ws + 753664);             // 262144 B
  u32* partial  = (u32*)(ws + 2097152);              // 33554432 B (bf16 packed)

  k_prep<<<704, 256, 0, stream>>>(ap_hid, ue_hid, W1, b1, W2, b2, W3, Wt,
                                  (float*)(ws + 360448), c1, c2);
  k_pass1<<<1024, 256, 0, stream>>>(edge, Wt, c1, c2, ap_sum, ue_sum, partial);
  k_mid<<<320, 256, 0, stream>>>(ap_sum, ue_sum, W3, b3, s3, s4b);
  k_pass2<<<1024, 256, 0, stream>>>(partial, s3, s4b, outp);
}

// Round 6
// 211.730 us; speedup vs baseline: 1.2732x; 1.1568x over previous
//
#include <hip/hip_runtime.h>

// EdgeConv on dense bipartite graph: A=256, U=1024, D=64.
// out[a,u] = edge@W3t - (relu(edge@W1b+c1[a]) + relu(edge@W2b+c2[u]))@W3b + s3[a] + s4[u]
// with c1 = ap_hid@W1t+b1, c2 = ue_hid@W2t+b2, s3 = ap_sum@W3b, s4 = ue_sum@W3b+b3.
//
// R6: ZERO atomics (R5 counters: 5.2M atomicAdds added ~160 MB of 16B-granule
// TCC traffic and serialized the K-loop). Pass1 writes plain partial buffers
// (appart 4 MB / uepart 16 MB), ALL global stores hoisted after the K-loop so
// the ds_read wait only covers the slice DMA. Triple-buffered global_load_lds
// (depth-2 prefetch). k_mid fuses the 16x/64x reductions + s3/s4 row-MLP.

typedef short short8 __attribute__((ext_vector_type(8)));
typedef float f32x4 __attribute__((ext_vector_type(4)));
typedef unsigned int u32;

__device__ __forceinline__ unsigned short f2bf(float f) {
  u32 u = __float_as_uint(f);
  return (unsigned short)((u + 0x7FFFu + ((u >> 16) & 1u)) >> 16);  // RNE
}

__device__ __forceinline__ f32x4 mfma16(short8 a, short8 b, f32x4 c) {
  return __builtin_amdgcn_mfma_f32_16x16x32_bf16(a, b, c, 0, 0, 0);
}

__device__ __forceinline__ short8 cvt8(float4 a, float4 b) {
  short8 r;
  r[0] = (short)f2bf(a.x); r[1] = (short)f2bf(a.y);
  r[2] = (short)f2bf(a.z); r[3] = (short)f2bf(a.w);
  r[4] = (short)f2bf(b.x); r[5] = (short)f2bf(b.y);
  r[6] = (short)f2bf(b.z); r[7] = (short)f2bf(b.w);
  return r;
}

// async global->LDS DMA, 16 B per lane, lands at ldsbase + lane*16
__device__ __forceinline__ void gl_lds16(const float* g, float* l) {
  __builtin_amdgcn_global_load_lds(
      (const __attribute__((address_space(1))) u32*)g,
      (__attribute__((address_space(3))) u32*)l, 16, 0, 0);
}

// Stage one 16-row x 256B slice panel for wave w. LDS slot cc (16B chunks)
// of row rl holds global chunk cc ^ (rl&7)  (involution; reader XORs again).
__device__ __forceinline__ void stage_slice(const float* __restrict__ edge,
                                            int a, int u0, int w, int lane,
                                            float* __restrict__ buf) {
#pragma unroll
  for (int q = 0; q < 4; q++) {
    int rl = q * 4 + (lane >> 4);
    int cg = (lane & 15) ^ (rl & 7);
    const float* g = edge + (a * 1024 + u0 + w * 16 + rl) * 64 + cg * 4;
    gl_lds16(g, buf + w * 1024 + q * 256);
  }
}

__device__ __forceinline__ void rowmlp_row(const float* __restrict__ in,
                                           const float* __restrict__ W,
                                           const float* __restrict__ bias,
                                           float* __restrict__ out, int r, int lane) {
  float rv = in[r * 64 + lane];
  float acc = bias ? bias[lane] : 0.f;
#pragma unroll
  for (int k = 0; k < 64; k++) acc += __shfl(rv, k, 64) * W[k * 64 + lane];
  out[r * 64 + lane] = acc;
}

// Setup: build Wt (bf16, n-major, 4 sections), c1, c2. No zeroing needed (no atomics).
// Wt rows 0-63: W1_bot^T, 64-127: W2_bot^T, 128-191: W3_top^T, 192-255: W3_bot^T
__global__ __launch_bounds__(256) void k_prep(
    const float* __restrict__ ap_hid, const float* __restrict__ ue_hid,
    const float* __restrict__ W1, const float* __restrict__ b1,
    const float* __restrict__ W2, const float* __restrict__ b2,
    const float* __restrict__ W3, unsigned short* __restrict__ Wt,
    float* __restrict__ c1, float* __restrict__ c2) {
  int bx = blockIdx.x, tid = threadIdx.x;
  if (bx < 64) {
    int idx = bx * 256 + tid;  // 16384 total
    int r = idx >> 6, k = idx & 63;
    int sec = r >> 6, d = r & 63;
    float v;
    if (sec == 0)      v = W1[(64 + k) * 64 + d];
    else if (sec == 1) v = W2[(64 + k) * 64 + d];
    else if (sec == 2) v = W3[k * 64 + d];
    else               v = W3[(64 + k) * 64 + d];
    Wt[r * 64 + k] = f2bf(v);
  } else if (bx < 128) {
    int r = (bx - 64) * 4 + (tid >> 6);
    rowmlp_row(ap_hid, W1, b1, c1, r, tid & 63);
  } else {  // bx in [128, 384)
    int r = (bx - 128) * 4 + (tid >> 6);
    rowmlp_row(ue_hid, W2, b2, c2, r, tid & 63);
  }
}

// Pass 1: ONE pass over edge. 1024 blocks = 64 a-groups(4 slices) x 16 u-panels.
// Per slice: P1,P2 -> t (wave-private LDS round-trip) -> P3 - t@W3b packed bf16.
// ap/ue sums accumulate in registers; ALL global stores after the K-loop.
__global__ __launch_bounds__(256, 2) void k_pass1(
    const float* __restrict__ edge, const unsigned short* __restrict__ Wt,
    const float* __restrict__ c1, const float* __restrict__ c2,
    float* __restrict__ appart, float* __restrict__ uepart,
    u32* __restrict__ partial) {
  __shared__ float Ebuf[3][4096];            // 3 x 16 KB slice buffers
  __shared__ unsigned short t_lds[64 * 72];  // 9216 B
  int tid = threadIdx.x, lane = tid & 63, w = tid >> 6;
  int fr = lane & 15, fq = lane >> 4;
  int bx = blockIdx.x;
  int g = bx >> 4, pnl = bx & 15;
  int a0 = g * 4, u0 = pnl * 64;

  // depth-2 DMA prefetch
  stage_slice(edge, a0, u0, w, lane, &Ebuf[0][0]);
  stage_slice(edge, a0 + 1, u0, w, lane, &Ebuf[1][0]);

  short8 bwA[4][2], bwB[4][2], bwT[4][2], bwG[4][2];
#pragma unroll
  for (int j = 0; j < 4; j++) {
#pragma unroll
    for (int ks = 0; ks < 2; ks++) {
      bwA[j][ks] = *(const short8*)(Wt + (j * 16 + fr) * 64 + ks * 32 + fq * 8);
      bwB[j][ks] = *(const short8*)(Wt + (64 + j * 16 + fr) * 64 + ks * 32 + fq * 8);
      bwT[j][ks] = *(const short8*)(Wt + (128 + j * 16 + fr) * 64 + ks * 32 + fq * 8);
      bwG[j][ks] = *(const short8*)(Wt + (192 + j * 16 + fr) * 64 + ks * 32 + fq * 8);
    }
  }
  float c2v[4][4];
#pragma unroll
  for (int j = 0; j < 4; j++)
#pragma unroll
    for (int i = 0; i < 4; i++)
      c2v[j][i] = c2[(u0 + w * 16 + fq * 4 + i) * 64 + j * 16 + fr];
  float c1v[4][4];
#pragma unroll
  for (int c = 0; c < 4; c++)
#pragma unroll
    for (int j = 0; j < 4; j++)
      c1v[c][j] = c1[(a0 + c) * 64 + j * 16 + fr];

  float ureg[4][4] = {};
  float apg[4][4];   // per-slice ap row-sums (all lanes hold result)
  u32 r8buf[4][8];   // per-slice packed bf16 partials

  int sw = fr & 7;
  for (int c = 0; c < 4; c++) {
    // read slice c (compiler waits on its DMA, issued 2 iterations ago;
    // no stores outstanding -> the wait is precise)
    const float* rb = &Ebuf[c % 3][w * 1024 + fr * 64];
    float4 f0 = *(const float4*)(rb + ((fq * 2) ^ sw) * 4);
    float4 f1 = *(const float4*)(rb + ((fq * 2 + 1) ^ sw) * 4);
    float4 f2 = *(const float4*)(rb + (8 + ((fq * 2) ^ sw)) * 4);
    float4 f3 = *(const float4*)(rb + (8 + ((fq * 2 + 1) ^ sw)) * 4);
    asm volatile("" ::: "memory");  // keep next DMA AFTER these ds_reads
    if (c < 2) stage_slice(edge, a0 + c + 2, u0, w, lane, &Ebuf[(c + 2) % 3][0]);
    asm volatile("" ::: "memory");

    short8 af0 = cvt8(f0, f1);
    short8 af1 = cvt8(f2, f3);

    f32x4 accP3[4];
#pragma unroll
    for (int j = 0; j < 4; j++) {
      f32x4 A1 = {0.f, 0.f, 0.f, 0.f};
      A1 = mfma16(af0, bwA[j][0], A1);
      A1 = mfma16(af1, bwA[j][1], A1);
      f32x4 A2 = {0.f, 0.f, 0.f, 0.f};
      A2 = mfma16(af0, bwB[j][0], A2);
      A2 = mfma16(af1, bwB[j][1], A2);
      f32x4 P3 = {0.f, 0.f, 0.f, 0.f};
      P3 = mfma16(af0, bwT[j][0], P3);
      P3 = mfma16(af1, bwT[j][1], P3);
      accP3[j] = P3;
      float rs = 0.f;
#pragma unroll
      for (int i = 0; i < 4; i++) {
        float r1 = fmaxf(A1[i] + c1v[c][j], 0.f);
        float r2 = fmaxf(A2[i] + c2v[j][i], 0.f);
        rs += r1;
        ureg[j][i] += r2;
        t_lds[(w * 16 + fq * 4 + i) * 72 + j * 16 + fr] = f2bf(r1 + r2);
      }
      rs += __shfl_xor(rs, 16, 64);
      rs += __shfl_xor(rs, 32, 64);
      apg[c][j] = rs;
    }
    // t round-trip (wave-private rows; DS in-order per wave, no barrier)
    short8 tf0 = *(const short8*)&t_lds[(w * 16 + fr) * 72 + fq * 8];
    short8 tf1 = *(const short8*)&t_lds[(w * 16 + fr) * 72 + 32 + fq * 8];
#pragma unroll
    for (int j = 0; j < 4; j++) {
      f32x4 gg = {0.f, 0.f, 0.f, 0.f};
      gg = mfma16(tf0, bwG[j][0], gg);
      gg = mfma16(tf1, bwG[j][1], gg);
#pragma unroll
      for (int i = 0; i < 4; i++) accP3[j][i] -= gg[i];
    }
#pragma unroll
    for (int i = 0; i < 4; i++)
#pragma unroll
      for (int jj = 0; jj < 2; jj++)
        r8buf[c][i * 2 + jj] = (u32)f2bf(accP3[2 * jj][i]) |
                               ((u32)f2bf(accP3[2 * jj + 1][i]) << 16);
  }

  // ---- all global stores (fire-and-forget, nothing waits on them) ----
#pragma unroll
  for (int c = 0; c < 4; c++) {
    u32* pp = partial + ((((a0 + c) * 16 + pnl) * 4 + w) * 64 + lane) * 8;
    *(uint4*)pp = make_uint4(r8buf[c][0], r8buf[c][1], r8buf[c][2], r8buf[c][3]);
    *(uint4*)(pp + 4) = make_uint4(r8buf[c][4], r8buf[c][5], r8buf[c][6], r8buf[c][7]);
  }
  if (lane < 16) {
#pragma unroll
    for (int c = 0; c < 4; c++)
#pragma unroll
      for (int j = 0; j < 4; j++)
        appart[(((a0 + c) * 16 + pnl) * 4 + w) * 64 + j * 16 + lane] = apg[c][j];
  }
#pragma unroll
  for (int j = 0; j < 4; j++)
#pragma unroll
    for (int i = 0; i < 4; i++)
      uepart[g * 65536 + (u0 + w * 16 + fq * 4 + i) * 64 + j * 16 + fr] = ureg[j][i];
}

// k_mid: fused reduce + row-MLP. Blocks 0-63: 4 a-rows each (16x4-way reduce of
// appart -> s3 = ap_sum@W3b). Blocks 64-319: 4 u-rows each (64-way reduce of
// uepart -> s4b = ue_sum@W3b + b3). Each block's rows are independent.
__global__ __launch_bounds__(256) void k_mid(
    const float* __restrict__ appart, const float* __restrict__ uepart,
    const float* __restrict__ W3, const float* __restrict__ b3,
    float* __restrict__ s3, float* __restrict__ s4b) {
  int bx = blockIdx.x, tid = threadIdx.x, lane = tid & 63;
  if (bx < 64) {
    int a = bx * 4 + (tid >> 6);
    float acc = 0.f;
#pragma unroll 4
    for (int r = 0; r < 64; r++) acc += appart[(a * 64 + r) * 64 + lane];
    float o = 0.f;
#pragma unroll
    for (int k = 0; k < 64; k++)
      o += __shfl(acc, k, 64) * W3[(64 + k) * 64 + lane];
    s3[a * 64 + lane] = o;
  } else {
    int u = (bx - 64) * 4 + (tid >> 6);
    float acc = 0.f;
#pragma unroll 4
    for (int gi = 0; gi < 64; gi++) acc += uepart[gi * 65536 + u * 64 + lane];
    float o = b3[lane];
#pragma unroll
    for (int k = 0; k < 64; k++)
      o += __shfl(acc, k, 64) * W3[(64 + k) * 64 + lane];
    s4b[u * 64 + lane] = o;
  }
}

// Pass 2: out = unpack(partial) + s3[a] + s4b[u]. Pure streaming.
__global__ __launch_bounds__(256) void k_pass2(
    const u32* __restrict__ partial, const float* __restrict__ s3,
    const float* __restrict__ s4b, float* __restrict__ out) {
  int t0 = blockIdx.x * 256 + threadIdx.x;
  uint4 pa[4], pb[4];
#pragma unroll
  for (int it = 0; it < 4; it++) {
    const uint4* pp = (const uint4*)(partial + (t0 + it * 262144) * 8);
    pa[it] = pp[0];
    pb[it] = pp[1];
  }
#pragma unroll
  for (int it = 0; it < 4; it++) {
    int rec = t0 + it * 262144;
    int l = rec & 63, w = (rec >> 6) & 3, p = (rec >> 8) & 15, a = rec >> 12;
    int fr = l & 15, fq = l >> 4;
    int ub = p * 64 + w * 16 + fq * 4;
    float s3v[4];
#pragma unroll
    for (int j = 0; j < 4; j++) s3v[j] = s3[a * 64 + j * 16 + fr];
    u32 d[8] = {pa[it].x, pa[it].y, pa[it].z, pa[it].w,
                pb[it].x, pb[it].y, pb[it].z, pb[it].w};
#pragma unroll
    for (int i = 0; i < 4; i++) {
      const float* s4r = s4b + (ub + i) * 64 + fr;
      float* outr = out + (a * 1024 + ub + i) * 64 + fr;
#pragma unroll
      for (int j = 0; j < 4; j++) {
        u32 dw = d[i * 2 + (j >> 1)];
        u32 bits = (j & 1) ? (dw & 0xFFFF0000u) : (dw << 16);
        float v = __uint_as_float(bits) + s3v[j] + s4r[j * 16];
        __builtin_nontemporal_store(v, outr + j * 16);
      }
    }
  }
}

extern "C" void kernel_launch(void* const* d_in, const int* in_sizes, int n_in,
                              void* d_out, int out_size, void* d_ws, size_t ws_size,
                              hipStream_t stream) {
  const float* ap_hid = (const float*)d_in[0];
  const float* ue_hid = (const float*)d_in[1];
  const float* edge   = (const float*)d_in[2];
  const float* W1     = (const float*)d_in[3];
  const float* b1     = (const float*)d_in[4];
  const float* W2     = (const float*)d_in[5];
  const float* b2     = (const float*)d_in[6];
  const float* W3     = (const float*)d_in[7];
  const float* b3     = (const float*)d_in[8];
  float* outp = (float*)d_out;

  char* ws = (char*)d_ws;
  unsigned short* Wt = (unsigned short*)ws;      //    32768 B
  float* c1     = (float*)(ws + 32768);          //    65536 B
  float* c2     = (float*)(ws + 98304);          //   262144 B
  float* s3     = (float*)(ws + 360448);         //    65536 B
  float* s4b    = (float*)(ws + 425984);         //   262144 B
  float* appart = (float*)(ws + 688128);         //  4194304 B
  float* uepart = (float*)(ws + 5242880);        // 16777216 B
  u32* partial  = (u32*)(ws + 23068672);         // 33554432 B (bf16 packed)

  k_prep<<<384, 256, 0, stream>>>(ap_hid, ue_hid, W1, b1, W2, b2, W3, Wt, c1, c2);
  k_pass1<<<1024, 256, 0, stream>>>(edge, Wt, c1, c2, appart, uepart, partial);
  k_mid<<<320, 256, 0, stream>>>(appart, uepart, W3, b3, s3, s4b);
  k_pass2<<<1024, 256, 0, stream>>>(partial, s3, s4b, outp);
}

// Round 7
// 193.316 us; speedup vs baseline: 1.3944x; 1.0953x over previous
//
#include <hip/hip_runtime.h>

// EdgeConv on dense bipartite graph: A=256, U=1024, D=64.
// out[a,u] = edge@W3t - (relu(edge@W1b+c1[a]) + relu(edge@W2b+c2[u]))@W3b + s3[a] + s4[u]
// with c1 = ap_hid@W1t+b1, c2 = ue_hid@W2t+b2, s3 = ap_sum@W3b, s4 = ue_sum@W3b+b3.
//
// R7: fix R6's two pathologies seen in counters:
//  1) 128 resident weight VGPRs -> spill/demotion (WRITE_SIZE 149.5 MB vs 54 real).
//     Now only A,B resident (64 VGPRs); T,G streamed per slice as batched L2 loads.
//  2) Ebuf bank conflicts (row stride 256B = 0 mod 32 banks). Now rotation
//     swizzle: LDS slot (r,s) holds global chunk (s-r)&15; DMA stays lane-linear,
//     reads hit 8 lanes per 4-bank group = b128 minimum (conflict-free).

typedef short short8 __attribute__((ext_vector_type(8)));
typedef float f32x4 __attribute__((ext_vector_type(4)));
typedef unsigned int u32;

__device__ __forceinline__ unsigned short f2bf(float f) {
  u32 u = __float_as_uint(f);
  return (unsigned short)((u + 0x7FFFu + ((u >> 16) & 1u)) >> 16);  // RNE
}

__device__ __forceinline__ f32x4 mfma16(short8 a, short8 b, f32x4 c) {
  return __builtin_amdgcn_mfma_f32_16x16x32_bf16(a, b, c, 0, 0, 0);
}

__device__ __forceinline__ short8 cvt8(float4 a, float4 b) {
  short8 r;
  r[0] = (short)f2bf(a.x); r[1] = (short)f2bf(a.y);
  r[2] = (short)f2bf(a.z); r[3] = (short)f2bf(a.w);
  r[4] = (short)f2bf(b.x); r[5] = (short)f2bf(b.y);
  r[6] = (short)f2bf(b.z); r[7] = (short)f2bf(b.w);
  return r;
}

// async global->LDS DMA, 16 B per lane, lands at ldsbase + lane*16
__device__ __forceinline__ void gl_lds16(const float* g, float* l) {
  __builtin_amdgcn_global_load_lds(
      (const __attribute__((address_space(1))) u32*)g,
      (__attribute__((address_space(3))) u32*)l, 16, 0, 0);
}

// Stage one 16-row x 256B slice for wave w with rotation swizzle:
// LDS slot (local row r, slot s) holds global chunk (s - r) & 15.
__device__ __forceinline__ void stage_slice(const float* __restrict__ edge,
                                            int a, int u0, int w, int lane,
                                            float* __restrict__ buf) {
#pragma unroll
  for (int q = 0; q < 4; q++) {
    int rl = q * 4 + (lane >> 4);
    int cg = ((lane & 15) - rl) & 15;
    const float* g = edge + (a * 1024 + u0 + w * 16 + rl) * 64 + cg * 4;
    gl_lds16(g, buf + w * 1024 + q * 256);
  }
}

__device__ __forceinline__ void rowmlp_row(const float* __restrict__ in,
                                           const float* __restrict__ W,
                                           const float* __restrict__ bias,
                                           float* __restrict__ out, int r, int lane) {
  float rv = in[r * 64 + lane];
  float acc = bias ? bias[lane] : 0.f;
#pragma unroll
  for (int k = 0; k < 64; k++) acc += __shfl(rv, k, 64) * W[k * 64 + lane];
  out[r * 64 + lane] = acc;
}

// Setup: build Wt (bf16, n-major, 4 sections), c1, c2.
// Wt rows 0-63: W1_bot^T, 64-127: W2_bot^T, 128-191: W3_top^T, 192-255: W3_bot^T
__global__ __launch_bounds__(256) void k_prep(
    const float* __restrict__ ap_hid, const float* __restrict__ ue_hid,
    const float* __restrict__ W1, const float* __restrict__ b1,
    const float* __restrict__ W2, const float* __restrict__ b2,
    const float* __restrict__ W3, unsigned short* __restrict__ Wt,
    float* __restrict__ c1, float* __restrict__ c2) {
  int bx = blockIdx.x, tid = threadIdx.x;
  if (bx < 64) {
    int idx = bx * 256 + tid;  // 16384 total
    int r = idx >> 6, k = idx & 63;
    int sec = r >> 6, d = r & 63;
    float v;
    if (sec == 0)      v = W1[(64 + k) * 64 + d];
    else if (sec == 1) v = W2[(64 + k) * 64 + d];
    else if (sec == 2) v = W3[k * 64 + d];
    else               v = W3[(64 + k) * 64 + d];
    Wt[r * 64 + k] = f2bf(v);
  } else if (bx < 128) {
    int r = (bx - 64) * 4 + (tid >> 6);
    rowmlp_row(ap_hid, W1, b1, c1, r, tid & 63);
  } else {  // bx in [128, 384)
    int r = (bx - 128) * 4 + (tid >> 6);
    rowmlp_row(ue_hid, W2, b2, c2, r, tid & 63);
  }
}

// Pass 1: ONE pass over edge. 1024 blocks = 64 a-groups(4 slices) x 16 u-panels.
__global__ __launch_bounds__(256, 2) void k_pass1(
    const float* __restrict__ edge, const unsigned short* __restrict__ Wt,
    const float* __restrict__ c1, const float* __restrict__ c2,
    float* __restrict__ appart, float* __restrict__ uepart,
    u32* __restrict__ partial) {
  __shared__ float Ebuf[3][4096];            // 3 x 16 KB slice buffers
  __shared__ unsigned short t_lds[64 * 72];  // 9216 B
  int tid = threadIdx.x, lane = tid & 63, w = tid >> 6;
  int fr = lane & 15, fq = lane >> 4;
  int bx = blockIdx.x;
  int g = bx >> 4, pnl = bx & 15;
  int a0 = g * 4, u0 = pnl * 64;

  // depth-2 DMA prefetch
  stage_slice(edge, a0, u0, w, lane, &Ebuf[0][0]);
  stage_slice(edge, a0 + 1, u0, w, lane, &Ebuf[1][0]);

  // resident A,B weight fragments only (64 VGPRs)
  short8 bwA[4][2], bwB[4][2];
#pragma unroll
  for (int j = 0; j < 4; j++) {
#pragma unroll
    for (int ks = 0; ks < 2; ks++) {
      bwA[j][ks] = *(const short8*)(Wt + (j * 16 + fr) * 64 + ks * 32 + fq * 8);
      bwB[j][ks] = *(const short8*)(Wt + (64 + j * 16 + fr) * 64 + ks * 32 + fq * 8);
    }
  }
  float c2v[4][4];
#pragma unroll
  for (int j = 0; j < 4; j++)
#pragma unroll
    for (int i = 0; i < 4; i++)
      c2v[j][i] = c2[(u0 + w * 16 + fq * 4 + i) * 64 + j * 16 + fr];
  float ureg[4][4] = {};

  // swizzled read offsets (loop-invariant)
  int sA = (fr * 16 + ((2 * fq + fr) & 15)) * 4;
  int sB = (fr * 16 + ((2 * fq + 1 + fr) & 15)) * 4;
  int sC = (fr * 16 + ((2 * fq + 8 + fr) & 15)) * 4;
  int sD = (fr * 16 + ((2 * fq + 9 + fr) & 15)) * 4;

#pragma unroll
  for (int c = 0; c < 4; c++) {
    int a = a0 + c;
    const float* rb = &Ebuf[c % 3][w * 1024];
    float4 f0 = *(const float4*)(rb + sA);
    float4 f1 = *(const float4*)(rb + sB);
    float4 f2 = *(const float4*)(rb + sC);
    float4 f3 = *(const float4*)(rb + sD);
    asm volatile("" ::: "memory");
    if (c < 2) stage_slice(edge, a0 + c + 2, u0, w, lane, &Ebuf[(c + 2) % 3][0]);
    asm volatile("" ::: "memory");

    // streamed T fragments for this slice (batched; arrival hidden by P1/P2)
    short8 bwT[4][2];
#pragma unroll
    for (int j = 0; j < 4; j++)
#pragma unroll
      for (int ks = 0; ks < 2; ks++)
        bwT[j][ks] = *(const short8*)(Wt + (128 + j * 16 + fr) * 64 + ks * 32 + fq * 8);
    float c1v[4];
#pragma unroll
    for (int j = 0; j < 4; j++) c1v[j] = c1[a * 64 + j * 16 + fr];

    short8 af0 = cvt8(f0, f1);
    short8 af1 = cvt8(f2, f3);

    f32x4 accP3[4];
#pragma unroll
    for (int j = 0; j < 4; j++) {
      f32x4 A1 = {0.f, 0.f, 0.f, 0.f};
      A1 = mfma16(af0, bwA[j][0], A1);
      A1 = mfma16(af1, bwA[j][1], A1);
      f32x4 A2 = {0.f, 0.f, 0.f, 0.f};
      A2 = mfma16(af0, bwB[j][0], A2);
      A2 = mfma16(af1, bwB[j][1], A2);
      f32x4 P3 = {0.f, 0.f, 0.f, 0.f};
      P3 = mfma16(af0, bwT[j][0], P3);
      P3 = mfma16(af1, bwT[j][1], P3);
      accP3[j] = P3;
      float rs = 0.f;
#pragma unroll
      for (int i = 0; i < 4; i++) {
        float r1 = fmaxf(A1[i] + c1v[j], 0.f);
        float r2 = fmaxf(A2[i] + c2v[j][i], 0.f);
        rs += r1;
        ureg[j][i] += r2;
        t_lds[(w * 16 + fq * 4 + i) * 72 + j * 16 + fr] = f2bf(r1 + r2);
      }
      rs += __shfl_xor(rs, 16, 64);
      rs += __shfl_xor(rs, 32, 64);
      if (lane < 16) appart[((a * 16 + pnl) * 4 + w) * 64 + j * 16 + lane] = rs;
    }
    // streamed G fragments (issued before t read-back; overlap lgkm wait)
    short8 bwG[4][2];
#pragma unroll
    for (int j = 0; j < 4; j++)
#pragma unroll
      for (int ks = 0; ks < 2; ks++)
        bwG[j][ks] = *(const short8*)(Wt + (192 + j * 16 + fr) * 64 + ks * 32 + fq * 8);

    // t round-trip (wave-private rows; DS in-order per wave, no barrier)
    short8 tf0 = *(const short8*)&t_lds[(w * 16 + fr) * 72 + fq * 8];
    short8 tf1 = *(const short8*)&t_lds[(w * 16 + fr) * 72 + 32 + fq * 8];
#pragma unroll
    for (int j = 0; j < 4; j++) {
      f32x4 gg = {0.f, 0.f, 0.f, 0.f};
      gg = mfma16(tf0, bwG[j][0], gg);
      gg = mfma16(tf1, bwG[j][1], gg);
#pragma unroll
      for (int i = 0; i < 4; i++) accP3[j][i] -= gg[i];
    }
    // pack + store this slice's partial (fire-and-forget)
    u32 r8[8];
#pragma unroll
    for (int i = 0; i < 4; i++)
#pragma unroll
      for (int jj = 0; jj < 2; jj++)
        r8[i * 2 + jj] = (u32)f2bf(accP3[2 * jj][i]) |
                         ((u32)f2bf(accP3[2 * jj + 1][i]) << 16);
    u32* pp = partial + (((a * 16 + pnl) * 4 + w) * 64 + lane) * 8;
    *(uint4*)pp = make_uint4(r8[0], r8[1], r8[2], r8[3]);
    *(uint4*)(pp + 4) = make_uint4(r8[4], r8[5], r8[6], r8[7]);
  }

#pragma unroll
  for (int j = 0; j < 4; j++)
#pragma unroll
    for (int i = 0; i < 4; i++)
      uepart[g * 65536 + (u0 + w * 16 + fq * 4 + i) * 64 + j * 16 + fr] = ureg[j][i];
}

// k_mid: fused reduce + row-MLP (s3 = ap_sum@W3b; s4b = ue_sum@W3b + b3).
__global__ __launch_bounds__(256) void k_mid(
    const float* __restrict__ appart, const float* __restrict__ uepart,
    const float* __restrict__ W3, const float* __restrict__ b3,
    float* __restrict__ s3, float* __restrict__ s4b) {
  int bx = blockIdx.x, tid = threadIdx.x, lane = tid & 63;
  if (bx < 64) {
    int a = bx * 4 + (tid >> 6);
    float acc = 0.f;
#pragma unroll 4
    for (int r = 0; r < 64; r++) acc += appart[(a * 64 + r) * 64 + lane];
    float o = 0.f;
#pragma unroll
    for (int k = 0; k < 64; k++)
      o += __shfl(acc, k, 64) * W3[(64 + k) * 64 + lane];
    s3[a * 64 + lane] = o;
  } else {
    int u = (bx - 64) * 4 + (tid >> 6);
    float acc = 0.f;
#pragma unroll 4
    for (int gi = 0; gi < 64; gi++) acc += uepart[gi * 65536 + u * 64 + lane];
    float o = b3[lane];
#pragma unroll
    for (int k = 0; k < 64; k++)
      o += __shfl(acc, k, 64) * W3[(64 + k) * 64 + lane];
    s4b[u * 64 + lane] = o;
  }
}

// Pass 2: out = unpack(partial) + s3[a] + s4b[u]. Pure streaming.
__global__ __launch_bounds__(256) void k_pass2(
    const u32* __restrict__ partial, const float* __restrict__ s3,
    const float* __restrict__ s4b, float* __restrict__ out) {
  int t0 = blockIdx.x * 256 + threadIdx.x;
  uint4 pa[4], pb[4];
#pragma unroll
  for (int it = 0; it < 4; it++) {
    const uint4* pp = (const uint4*)(partial + (t0 + it * 262144) * 8);
    pa[it] = pp[0];
    pb[it] = pp[1];
  }
#pragma unroll
  for (int it = 0; it < 4; it++) {
    int rec = t0 + it * 262144;
    int l = rec & 63, w = (rec >> 6) & 3, p = (rec >> 8) & 15, a = rec >> 12;
    int fr = l & 15, fq = l >> 4;
    int ub = p * 64 + w * 16 + fq * 4;
    float s3v[4];
#pragma unroll
    for (int j = 0; j < 4; j++) s3v[j] = s3[a * 64 + j * 16 + fr];
    u32 d[8] = {pa[it].x, pa[it].y, pa[it].z, pa[it].w,
                pb[it].x, pb[it].y, pb[it].z, pb[it].w};
#pragma unroll
    for (int i = 0; i < 4; i++) {
      const float* s4r = s4b + (ub + i) * 64 + fr;
      float* outr = out + (a * 1024 + ub + i) * 64 + fr;
#pragma unroll
      for (int j = 0; j < 4; j++) {
        u32 dw = d[i * 2 + (j >> 1)];
        u32 bits = (j & 1) ? (dw & 0xFFFF0000u) : (dw << 16);
        float v = __uint_as_float(bits) + s3v[j] + s4r[j * 16];
        __builtin_nontemporal_store(v, outr + j * 16);
      }
    }
  }
}

extern "C" void kernel_launch(void* const* d_in, const int* in_sizes, int n_in,
                              void* d_out, int out_size, void* d_ws, size_t ws_size,
                              hipStream_t stream) {
  const float* ap_hid = (const float*)d_in[0];
  const float* ue_hid = (const float*)d_in[1];
  const float* edge   = (const float*)d_in[2];
  const float* W1     = (const float*)d_in[3];
  const float* b1     = (const float*)d_in[4];
  const float* W2     = (const float*)d_in[5];
  const float* b2     = (const float*)d_in[6];
  const float* W3     = (const float*)d_in[7];
  const float* b3     = (const float*)d_in[8];
  float* outp = (float*)d_out;

  char* ws = (char*)d_ws;
  unsigned short* Wt = (unsigned short*)ws;      //    32768 B
  float* c1     = (float*)(ws + 32768);          //    65536 B
  float* c2     = (float*)(ws + 98304);          //   262144 B
  float* s3     = (float*)(ws + 360448);         //    65536 B
  float* s4b    = (float*)(ws + 425984);         //   262144 B
  float* appart = (float*)(ws + 688128);         //  4194304 B
  float* uepart = (float*)(ws + 5242880);        // 16777216 B
  u32* partial  = (u32*)(ws + 23068672);         // 33554432 B (bf16 packed)

  k_prep<<<384, 256, 0, stream>>>(ap_hid, ue_hid, W1, b1, W2, b2, W3, Wt, c1, c2);
  k_pass1<<<1024, 256, 0, stream>>>(edge, Wt, c1, c2, appart, uepart, partial);
  k_mid<<<320, 256, 0, stream>>>(appart, uepart, W3, b3, s3, s4b);
  k_pass2<<<1024, 256, 0, stream>>>(partial, s3, s4b, outp);
}